// Round 15
// baseline (85.024 us; speedup 1.0000x reference)
//
#include <hip/hip_runtime.h>
#include <hip/hip_bf16.h>

#define B_ 8
#define T_ 4096
#define C_ 256
#define H_ 256
#define K_ 3
#define NC 128          // time chunks (32 t each)
#define TC 32
#define BM 128          // t rows per block (register-blocked: 2 t-halves per wave)
#define WFRAG_ELEMS (24 * 32 * 64 * 8)   // [ks][ntg][lane][j] bf16
#define SMEM_BYTES 66560                 // 130 rows x 512 B  (> buf 64 KB)

typedef __attribute__((ext_vector_type(8))) __bf16 bf16x8;
typedef __attribute__((ext_vector_type(4))) float f32x4;

__device__ __forceinline__ float sigm(float x) { return 1.0f / (1.0f + __expf(-x)); }

__device__ __forceinline__ ushort f2bf(float f) {
    union { float f; unsigned u; } v; v.f = f;
    return (ushort)((v.u + 0x7FFFu + ((v.u >> 16) & 1u)) >> 16);
}
__device__ __forceinline__ float bf2f(ushort u) {
    union { unsigned u; float f; } v; v.u = ((unsigned)u) << 16; return v.f;
}
__device__ __forceinline__ unsigned cvt_pk_bf16(float lo, float hi) {
    unsigned r;
    asm("v_cvt_pk_bf16_f32 %0, %1, %2" : "=v"(r) : "v"(lo), "v"(hi));
    return r;
}

// Gather f_w,z_w into B-fragment-linear bf16 layout for mfma_f32_16x16x32_bf16.
__global__ __launch_bounds__(256) void wfrag_kernel(const float* __restrict__ fw,
                                                    const float* __restrict__ zw,
                                                    ushort* __restrict__ wfrag) {
    int idx = blockIdx.x * 256 + threadIdx.x;
    if (idx >= WFRAG_ELEMS) return;
    int j   = idx & 7;
    int l   = (idx >> 3) & 63;
    int ntg = (idx >> 9) & 31;
    int ks  = idx >> 14;
    int n = ntg * 16 + (l & 15);
    int kappa = ks * 32 + (l >> 4) * 8 + j;
    int k = kappa >> 8, c = kappa & 255;
    const float* w = (n < 256) ? fw : zw;
    int h = n & 255;
    wfrag[idx] = f2bf(w[(h * C_ + c) * K_ + k]);
}

__device__ __forceinline__ void bload(const ushort* wb, int ks, const int (&ntg)[4],
                                      bf16x8 (&dst)[4]) {
#pragma unroll
    for (int ni = 0; ni < 4; ++ni)
        dst[ni] = *(const bf16x8*)(wb + (size_t)ks * 16384 + (size_t)ntg[ni] * 512);
}

// One K-step for BOTH t-halves: 8 A ds_reads, 32 MFMA per wave.
__device__ __forceinline__ void conv_step2(const char* smem, int ks, int lr, int lg,
                                           const bf16x8 (&bfr)[4], f32x4 (&acc)[2][4][4]) {
    const int k = ks >> 3;
    const int cb = ((ks & 7) * 32 + lg * 8) * 2;
    bf16x8 afr[2][4];
#pragma unroll
    for (int tt = 0; tt < 2; ++tt)
#pragma unroll
        for (int mi = 0; mi < 4; ++mi) {
            int row = tt * 64 + mi * 16 + lr + k;
            afr[tt][mi] = *(const bf16x8*)(smem + row * 512 + (cb ^ ((row & 7) << 4)));
        }
    __builtin_amdgcn_s_setprio(1);
#pragma unroll
    for (int ni = 0; ni < 4; ++ni)
#pragma unroll
        for (int tt = 0; tt < 2; ++tt)
#pragma unroll
            for (int mi = 0; mi < 4; ++mi)
                acc[tt][mi][ni] = __builtin_amdgcn_mfma_f32_16x16x32_bf16(afr[tt][mi], bfr[ni],
                                                                          acc[tt][mi][ni], 0, 0, 0);
    __builtin_amdgcn_s_setprio(0);
}

// ---------------------------------------------------------------------------
// Register-blocked fused conv (f,z) + gates + per-chunk affine scan.
// Block: 128 t x 256 h, 8 waves, each wave 2 t-halves x 64 n-cols (acc[2][4][4]).
// Every B fragment feeds 2 A fragments -> per-output B-L2 traffic halved and
// 32-MFMA clusters self-hide the B prefetch latency.
// Epilogue in 2 phases (t-half p): pack {a,f} -> 64x256 buf -> scan chunks
// 4bx+2p+{0,1}. Dynamic LDS 66560 B (130-row x tile, buf aliases it).
// ---------------------------------------------------------------------------
__global__ __launch_bounds__(512, 2) void conv_scan_kernel(const float* __restrict__ x,
                                                           const ushort* __restrict__ wfrag,
                                                           const float* __restrict__ fb,
                                                           const float* __restrict__ zb,
                                                           unsigned* __restrict__ AP,
                                                           float2* __restrict__ ab) {
    extern __shared__ __align__(16) char smem[];   // 66560: xs 130x512B | buf 64x256 uint
    unsigned* buf = (unsigned*)smem;

    const int b = blockIdx.y;
    const int bx = blockIdx.x;
    const int t0 = bx * BM;
    const int tid = threadIdx.x;

    // Stage x[b, t0-1 .. t0+128, :] as bf16, swizzled: byte = row*512 + ((2c)^((row&7)<<4))
    if (bx == 0 || bx == gridDim.x - 1) {
        for (int idx = tid; idx < 130 * 64; idx += 512) {
            int row = idx >> 6;
            int c4 = (idx & 63) * 4;
            int t = t0 - 1 + row;
            float4 v = make_float4(0.f, 0.f, 0.f, 0.f);
            if (t >= 0 && t < T_) v = *(const float4*)(x + ((size_t)(b * T_ + t)) * C_ + c4);
            uint2 w2 = make_uint2(cvt_pk_bf16(v.x, v.y), cvt_pk_bf16(v.z, v.w));
            *(uint2*)(smem + row * 512 + ((c4 * 2) ^ ((row & 7) << 4))) = w2;
        }
    } else {
        for (int idx = tid; idx < 130 * 64; idx += 512) {
            int row = idx >> 6;
            int c4 = (idx & 63) * 4;
            int t = t0 - 1 + row;
            float4 v = *(const float4*)(x + ((size_t)(b * T_ + t)) * C_ + c4);
            uint2 w2 = make_uint2(cvt_pk_bf16(v.x, v.y), cvt_pk_bf16(v.z, v.w));
            *(uint2*)(smem + row * 512 + ((c4 * 2) ^ ((row & 7) << 4))) = w2;
        }
    }
    __syncthreads();

    const int wv = tid >> 6;
    const int l  = tid & 63;
    const int lr = l & 15;
    const int lg = l >> 4;
    const int h0 = wv * 32;

    f32x4 acc[2][4][4];
#pragma unroll
    for (int ni = 0; ni < 4; ++ni) {
        float bv = (ni < 2 ? fb : zb)[h0 + (ni & 1) * 16 + lr];
        f32x4 bvv = {bv, bv, bv, bv};
#pragma unroll
        for (int tt = 0; tt < 2; ++tt)
#pragma unroll
            for (int mi = 0; mi < 4; ++mi) acc[tt][mi][ni] = bvv;
    }

    const ushort* wb = wfrag + (size_t)l * 8;
    int ntg_[4];
#pragma unroll
    for (int ni = 0; ni < 4; ++ni)
        ntg_[ni] = (ni < 2) ? (wv * 2 + ni) : (16 + wv * 2 + ni - 2);

    // Conv with ping-pong B prefetch (proven schedule), 2 t-halves per step.
    bf16x8 ba[4], bb[4];
    bload(wb, 0, ntg_, ba);
#pragma unroll 1
    for (int ks = 0; ks < 24; ks += 2) {
        bload(wb, ks + 1, ntg_, bb);
        conv_step2(smem, ks, lr, lg, ba, acc);
        if (ks + 2 < 24) bload(wb, ks + 2, ntg_, ba);
        conv_step2(smem, ks + 1, lr, lg, bb, acc);
    }

    // Two epilogue+scan phases, one per t-half (all waves active in both).
#pragma unroll 1
    for (int p = 0; p < 2; ++p) {
        __syncthreads();                   // xs (or prior buf) dead
#pragma unroll
        for (int mi = 0; mi < 4; ++mi) {
#pragma unroll
            for (int ni = 0; ni < 2; ++ni) {
                const int h = h0 + ni * 16 + lr;
#pragma unroll
                for (int r = 0; r < 4; ++r) {
                    float fv = sigm(acc[p][mi][ni][r]);
                    float av = sigm(acc[p][mi][ni + 2][r]) * (1.0f - fv);
                    int tl = (mi & 1) * 16 + lg * 4 + r;      // t within chunk
                    int trow = (mi >> 1) * 32 + tl;           // buf row
                    buf[trow * 256 + (h ^ ((tl << 2) & 31))] = cvt_pk_bf16(av, fv);
                }
            }
        }
        __syncthreads();

        // Parallel per-chunk scan: ch = tid>>8, h = tid&255.
        const int ch = tid >> 8;
        const int h = tid & 255;
        const int chunk = bx * 4 + 2 * p + ch;
        const int r0 = chunk * TC;
        const unsigned* bp = buf + ch * 32 * 256;
        unsigned* app = AP + ((size_t)b * T_ + r0) * H_ + h;
        unsigned u = bp[h];
        float A = bf2f((ushort)(u & 0xffff));
        float Pp = 1.0f;
        float f_prev = bf2f((ushort)(u >> 16));
        app[0] = cvt_pk_bf16(A, Pp);
#pragma unroll 8
        for (int j = 1; j < TC; ++j) {
            u = bp[j * 256 + (h ^ ((j << 2) & 31))];
            float a = bf2f((ushort)(u & 0xffff));
            float f = bf2f((ushort)(u >> 16));
            A = fmaf(f_prev, A, a);
            Pp *= f_prev;
            f_prev = f;
            app[(size_t)j * H_] = cvt_pk_bf16(A, Pp);
        }
        ab[((size_t)b * NC + chunk) * H_ + h] = make_float2(f_prev * A, f_prev * Pp);
    }
}

// ---------------------------------------------------------------------------
// Chain + apply: block p handles chunk c with (c>>2)%8 == p%8 so it lands on
// the same XCD (round-robin heuristic) as the conv block that wrote its AP
// slice. Bijection: r=p&7, q=p>>3, c = 4*(r + 8*(q>>2)) + (q&3).
// ---------------------------------------------------------------------------
__global__ __launch_bounds__(256) void chainapply_kernel(const unsigned* __restrict__ AP,
                                                         const float2* __restrict__ ab,
                                                         const float* __restrict__ init_f,
                                                         const float* __restrict__ init_z,
                                                         float* __restrict__ out) {
    const int p = blockIdx.x;
    const int q = p >> 3;
    const int c = 4 * ((p & 7) + 8 * (q >> 2)) + (q & 3);    // bijective, (c>>2)%8==p%8
    const int b = blockIdx.y;
    const int h = threadIdx.x;

    float f0 = sigm(init_f[b * H_ + h]);
    float z0 = sigm(init_z[b * H_ + h]);
    float s0 = z0 * (1.0f - f0);
    if (c == 0) out[(size_t)b * (T_ + 1) * H_ + h] = s0;

    float uv = f0 * s0;                              // u_0
    const float2* abp = ab + (size_t)b * NC * H_ + h;
#pragma unroll 8
    for (int cc = 0; cc < c; ++cc) {
        float2 qv = abp[(size_t)cc * H_];
        uv = fmaf(qv.y, uv, qv.x);
    }

    const unsigned* app = AP + ((size_t)b * T_ + c * TC) * H_ + h;
    float* op = out + ((size_t)b * (T_ + 1) + c * TC + 1) * H_ + h;
#pragma unroll 8
    for (int j = 0; j < TC; ++j) {
        unsigned w = app[(size_t)j * H_];
        op[(size_t)j * H_] = fmaf(bf2f((ushort)(w >> 16)), uv, bf2f((ushort)(w & 0xffff)));
    }
}

extern "C" void kernel_launch(void* const* d_in, const int* in_sizes, int n_in,
                              void* d_out, int out_size, void* d_ws, size_t ws_size,
                              hipStream_t stream) {
    const float* inputs = (const float*)d_in[0];   // [B,T,C]
    const float* init_f = (const float*)d_in[1];   // [B,H]
    const float* init_z = (const float*)d_in[2];   // [B,H]
    const float* f_w    = (const float*)d_in[3];   // [H,C,K]
    const float* f_b    = (const float*)d_in[4];   // [H]
    const float* z_w    = (const float*)d_in[5];   // [H,C,K]
    const float* z_b    = (const float*)d_in[6];   // [H]
    float* out = (float*)d_out;                    // [B,T+1,H]

    // ws: wfrag 768KB | AP (B*T*H uint, 32MB) | ab (B*NC*H float2, 2MB)
    ushort* wfrag = (ushort*)d_ws;
    unsigned* AP  = (unsigned*)(wfrag + WFRAG_ELEMS);
    float2* ab    = (float2*)(AP + (size_t)B_ * T_ * H_);

    wfrag_kernel<<<(WFRAG_ELEMS + 255) / 256, 256, 0, stream>>>(f_w, z_w, wfrag);

    // Opt in to >64KB dynamic LDS (capture-safe host-side attribute).
    hipFuncSetAttribute((const void*)conv_scan_kernel,
                        hipFuncAttributeMaxDynamicSharedMemorySize, SMEM_BYTES);
    dim3 cgrid(T_ / BM, B_, 1);
    conv_scan_kernel<<<cgrid, 512, SMEM_BYTES, stream>>>(inputs, wfrag, f_b, z_b, AP, ab);

    dim3 agrid(NC, B_, 1);
    chainapply_kernel<<<agrid, 256, 0, stream>>>(AP, ab, init_f, init_z, out);
}

// Round 16
// 65.908 us; speedup vs baseline: 1.2900x; 1.2900x over previous
//
#include <hip/hip_runtime.h>
#include <hip/hip_bf16.h>

#define B_ 8
#define T_ 4096
#define C_ 256
#define H_ 256
#define K_ 3
#define NC 128          // time chunks (32 t each)
#define TC 32
#define BM 128          // t rows per block (register-blocked: 2 t-halves per wave)
#define WFRAG_ELEMS (24 * 32 * 64 * 8)   // [ks][ntg][lane][j] bf16
#define SMEM_BYTES 66560                 // 130 rows x 512 B  (> buf 64 KB)

typedef __attribute__((ext_vector_type(8))) __bf16 bf16x8;
typedef __attribute__((ext_vector_type(4))) float f32x4;

__device__ __forceinline__ float sigm(float x) { return 1.0f / (1.0f + __expf(-x)); }

__device__ __forceinline__ ushort f2bf(float f) {
    union { float f; unsigned u; } v; v.f = f;
    return (ushort)((v.u + 0x7FFFu + ((v.u >> 16) & 1u)) >> 16);
}
__device__ __forceinline__ float bf2f(ushort u) {
    union { unsigned u; float f; } v; v.u = ((unsigned)u) << 16; return v.f;
}
__device__ __forceinline__ unsigned cvt_pk_bf16(float lo, float hi) {
    unsigned r;
    asm("v_cvt_pk_bf16_f32 %0, %1, %2" : "=v"(r) : "v"(lo), "v"(hi));
    return r;
}

// Gather f_w,z_w into B-fragment-linear bf16 layout for mfma_f32_16x16x32_bf16.
__global__ __launch_bounds__(256) void wfrag_kernel(const float* __restrict__ fw,
                                                    const float* __restrict__ zw,
                                                    ushort* __restrict__ wfrag) {
    int idx = blockIdx.x * 256 + threadIdx.x;
    if (idx >= WFRAG_ELEMS) return;
    int j   = idx & 7;
    int l   = (idx >> 3) & 63;
    int ntg = (idx >> 9) & 31;
    int ks  = idx >> 14;
    int n = ntg * 16 + (l & 15);
    int kappa = ks * 32 + (l >> 4) * 8 + j;
    int k = kappa >> 8, c = kappa & 255;
    const float* w = (n < 256) ? fw : zw;
    int h = n & 255;
    wfrag[idx] = f2bf(w[(h * C_ + c) * K_ + k]);
}

__device__ __forceinline__ void bload(const ushort* wb, int ks, const int (&ntg)[4],
                                      bf16x8 (&dst)[4]) {
#pragma unroll
    for (int ni = 0; ni < 4; ++ni)
        dst[ni] = *(const bf16x8*)(wb + (size_t)ks * 16384 + (size_t)ntg[ni] * 512);
}

// One K-step for BOTH t-halves: 8 A ds_reads, 32 MFMA per wave. All indices static.
__device__ __forceinline__ void conv_step2(const char* smem, int ks, int lr, int lg,
                                           const bf16x8 (&bfr)[4], f32x4 (&acc)[2][4][4]) {
    const int k = ks >> 3;
    const int cb = ((ks & 7) * 32 + lg * 8) * 2;
    bf16x8 afr[2][4];
#pragma unroll
    for (int tt = 0; tt < 2; ++tt)
#pragma unroll
        for (int mi = 0; mi < 4; ++mi) {
            int row = tt * 64 + mi * 16 + lr + k;
            afr[tt][mi] = *(const bf16x8*)(smem + row * 512 + (cb ^ ((row & 7) << 4)));
        }
    __builtin_amdgcn_s_setprio(1);
#pragma unroll
    for (int ni = 0; ni < 4; ++ni)
#pragma unroll
        for (int tt = 0; tt < 2; ++tt)
#pragma unroll
            for (int mi = 0; mi < 4; ++mi)
                acc[tt][mi][ni] = __builtin_amdgcn_mfma_f32_16x16x32_bf16(afr[tt][mi], bfr[ni],
                                                                          acc[tt][mi][ni], 0, 0, 0);
    __builtin_amdgcn_s_setprio(0);
}

// Epilogue + chunk scan for t-half P (COMPILE-TIME index into acc — rule #20).
template <int P>
__device__ __forceinline__ void epi_scan(f32x4 (&acc)[2][4][4], unsigned* buf,
                                         int lr, int lg, int h0, int tid,
                                         int b, int bx,
                                         unsigned* __restrict__ AP,
                                         float2* __restrict__ ab) {
    __syncthreads();                   // xs (or prior buf) dead
#pragma unroll
    for (int mi = 0; mi < 4; ++mi) {
#pragma unroll
        for (int ni = 0; ni < 2; ++ni) {
            const int h = h0 + ni * 16 + lr;
#pragma unroll
            for (int r = 0; r < 4; ++r) {
                float fv = sigm(acc[P][mi][ni][r]);
                float av = sigm(acc[P][mi][ni + 2][r]) * (1.0f - fv);
                int tl = (mi & 1) * 16 + lg * 4 + r;      // t within chunk
                int trow = (mi >> 1) * 32 + tl;           // buf row
                buf[trow * 256 + (h ^ ((tl << 2) & 31))] = cvt_pk_bf16(av, fv);
            }
        }
    }
    __syncthreads();

    // Parallel per-chunk scan: ch = tid>>8, h = tid&255.
    const int ch = tid >> 8;
    const int h = tid & 255;
    const int chunk = bx * 4 + 2 * P + ch;
    const int r0 = chunk * TC;
    const unsigned* bp = buf + ch * 32 * 256;
    unsigned* app = AP + ((size_t)b * T_ + r0) * H_ + h;
    unsigned u = bp[h];
    float A = bf2f((ushort)(u & 0xffff));
    float Pp = 1.0f;
    float f_prev = bf2f((ushort)(u >> 16));
    app[0] = cvt_pk_bf16(A, Pp);
#pragma unroll 8
    for (int j = 1; j < TC; ++j) {
        u = bp[j * 256 + (h ^ ((j << 2) & 31))];
        float a = bf2f((ushort)(u & 0xffff));
        float f = bf2f((ushort)(u >> 16));
        A = fmaf(f_prev, A, a);
        Pp *= f_prev;
        f_prev = f;
        app[(size_t)j * H_] = cvt_pk_bf16(A, Pp);
    }
    ab[((size_t)b * NC + chunk) * H_ + h] = make_float2(f_prev * A, f_prev * Pp);
}

// ---------------------------------------------------------------------------
// Register-blocked fused conv (f,z) + gates + per-chunk affine scan.
// Block: 128 t x 256 h, 8 waves, each wave 2 t-halves x 64 n-cols (acc[2][4][4]).
// Every B fragment feeds 2 A fragments -> per-output B-L2 traffic halved and
// 32-MFMA clusters self-hide the B prefetch latency.
// ---------------------------------------------------------------------------
__global__ __launch_bounds__(512, 2) void conv_scan_kernel(const float* __restrict__ x,
                                                           const ushort* __restrict__ wfrag,
                                                           const float* __restrict__ fb,
                                                           const float* __restrict__ zb,
                                                           unsigned* __restrict__ AP,
                                                           float2* __restrict__ ab) {
    extern __shared__ __align__(16) char smem[];   // 66560: xs 130x512B | buf 64x256 uint
    unsigned* buf = (unsigned*)smem;

    const int b = blockIdx.y;
    const int bx = blockIdx.x;
    const int t0 = bx * BM;
    const int tid = threadIdx.x;

    // Stage x[b, t0-1 .. t0+128, :] as bf16, swizzled: byte = row*512 + ((2c)^((row&7)<<4))
    if (bx == 0 || bx == gridDim.x - 1) {
        for (int idx = tid; idx < 130 * 64; idx += 512) {
            int row = idx >> 6;
            int c4 = (idx & 63) * 4;
            int t = t0 - 1 + row;
            float4 v = make_float4(0.f, 0.f, 0.f, 0.f);
            if (t >= 0 && t < T_) v = *(const float4*)(x + ((size_t)(b * T_ + t)) * C_ + c4);
            uint2 w2 = make_uint2(cvt_pk_bf16(v.x, v.y), cvt_pk_bf16(v.z, v.w));
            *(uint2*)(smem + row * 512 + ((c4 * 2) ^ ((row & 7) << 4))) = w2;
        }
    } else {
        for (int idx = tid; idx < 130 * 64; idx += 512) {
            int row = idx >> 6;
            int c4 = (idx & 63) * 4;
            int t = t0 - 1 + row;
            float4 v = *(const float4*)(x + ((size_t)(b * T_ + t)) * C_ + c4);
            uint2 w2 = make_uint2(cvt_pk_bf16(v.x, v.y), cvt_pk_bf16(v.z, v.w));
            *(uint2*)(smem + row * 512 + ((c4 * 2) ^ ((row & 7) << 4))) = w2;
        }
    }
    __syncthreads();

    const int wv = tid >> 6;
    const int l  = tid & 63;
    const int lr = l & 15;
    const int lg = l >> 4;
    const int h0 = wv * 32;

    f32x4 acc[2][4][4];
#pragma unroll
    for (int ni = 0; ni < 4; ++ni) {
        float bv = (ni < 2 ? fb : zb)[h0 + (ni & 1) * 16 + lr];
        f32x4 bvv = {bv, bv, bv, bv};
#pragma unroll
        for (int tt = 0; tt < 2; ++tt)
#pragma unroll
            for (int mi = 0; mi < 4; ++mi) acc[tt][mi][ni] = bvv;
    }

    const ushort* wb = wfrag + (size_t)l * 8;
    int ntg_[4];
#pragma unroll
    for (int ni = 0; ni < 4; ++ni)
        ntg_[ni] = (ni < 2) ? (wv * 2 + ni) : (16 + wv * 2 + ni - 2);

    // Conv with ping-pong B prefetch (proven schedule), 2 t-halves per step.
    bf16x8 ba[4], bb[4];
    bload(wb, 0, ntg_, ba);
#pragma unroll 1
    for (int ks = 0; ks < 24; ks += 2) {
        bload(wb, ks + 1, ntg_, bb);
        conv_step2(smem, ks, lr, lg, ba, acc);
        if (ks + 2 < 24) bload(wb, ks + 2, ntg_, ba);
        conv_step2(smem, ks + 1, lr, lg, bb, acc);
    }

    // Two epilogue+scan phases, compile-time t-half index (no scratch).
    epi_scan<0>(acc, buf, lr, lg, h0, tid, b, bx, AP, ab);
    epi_scan<1>(acc, buf, lr, lg, h0, tid, b, bx, AP, ab);
}

// ---------------------------------------------------------------------------
// Chain + apply: block p handles chunk c with (c>>2)%8 == p%8 so it lands on
// the same XCD (round-robin heuristic) as the conv block that wrote its AP
// slice. Bijection: r=p&7, q=p>>3, c = 4*(r + 8*(q>>2)) + (q&3).
// ---------------------------------------------------------------------------
__global__ __launch_bounds__(256) void chainapply_kernel(const unsigned* __restrict__ AP,
                                                         const float2* __restrict__ ab,
                                                         const float* __restrict__ init_f,
                                                         const float* __restrict__ init_z,
                                                         float* __restrict__ out) {
    const int p = blockIdx.x;
    const int q = p >> 3;
    const int c = 4 * ((p & 7) + 8 * (q >> 2)) + (q & 3);    // bijective, (c>>2)%8==p%8
    const int b = blockIdx.y;
    const int h = threadIdx.x;

    float f0 = sigm(init_f[b * H_ + h]);
    float z0 = sigm(init_z[b * H_ + h]);
    float s0 = z0 * (1.0f - f0);
    if (c == 0) out[(size_t)b * (T_ + 1) * H_ + h] = s0;

    float uv = f0 * s0;                              // u_0
    const float2* abp = ab + (size_t)b * NC * H_ + h;
#pragma unroll 8
    for (int cc = 0; cc < c; ++cc) {
        float2 qv = abp[(size_t)cc * H_];
        uv = fmaf(qv.y, uv, qv.x);
    }

    const unsigned* app = AP + ((size_t)b * T_ + c * TC) * H_ + h;
    float* op = out + ((size_t)b * (T_ + 1) + c * TC + 1) * H_ + h;
#pragma unroll 8
    for (int j = 0; j < TC; ++j) {
        unsigned w = app[(size_t)j * H_];
        op[(size_t)j * H_] = fmaf(bf2f((ushort)(w >> 16)), uv, bf2f((ushort)(w & 0xffff)));
    }
}

extern "C" void kernel_launch(void* const* d_in, const int* in_sizes, int n_in,
                              void* d_out, int out_size, void* d_ws, size_t ws_size,
                              hipStream_t stream) {
    const float* inputs = (const float*)d_in[0];   // [B,T,C]
    const float* init_f = (const float*)d_in[1];   // [B,H]
    const float* init_z = (const float*)d_in[2];   // [B,H]
    const float* f_w    = (const float*)d_in[3];   // [H,C,K]
    const float* f_b    = (const float*)d_in[4];   // [H]
    const float* z_w    = (const float*)d_in[5];   // [H,C,K]
    const float* z_b    = (const float*)d_in[6];   // [H]
    float* out = (float*)d_out;                    // [B,T+1,H]

    // ws: wfrag 768KB | AP (B*T*H uint, 32MB) | ab (B*NC*H float2, 2MB)
    ushort* wfrag = (ushort*)d_ws;
    unsigned* AP  = (unsigned*)(wfrag + WFRAG_ELEMS);
    float2* ab    = (float2*)(AP + (size_t)B_ * T_ * H_);

    wfrag_kernel<<<(WFRAG_ELEMS + 255) / 256, 256, 0, stream>>>(f_w, z_w, wfrag);

    // Opt in to >64KB dynamic LDS (capture-safe host-side attribute).
    hipFuncSetAttribute((const void*)conv_scan_kernel,
                        hipFuncAttributeMaxDynamicSharedMemorySize, SMEM_BYTES);
    dim3 cgrid(T_ / BM, B_, 1);
    conv_scan_kernel<<<cgrid, 512, SMEM_BYTES, stream>>>(inputs, wfrag, f_b, z_b, AP, ab);

    dim3 agrid(NC, B_, 1);
    chainapply_kernel<<<agrid, 256, 0, stream>>>(AP, ab, init_f, init_z, out);
}